// Round 1
// 837.046 us; speedup vs baseline: 1.0870x; 1.0870x over previous
//
#include <hip/hip_runtime.h>

typedef unsigned short u16;
typedef __bf16 bf16x8 __attribute__((ext_vector_type(8)));
typedef float f32x4 __attribute__((ext_vector_type(4)));

#define T_TOKENS 8192
#define DM 1024
#define DH 4096
#define DO 1024
#define NE 8

// workspace layout (bytes)
#define XB_OFF   0ull
#define W1B_OFF  16777216ull
#define W2B_OFF  16777216ull      /* aliases w1b region; cast after gemm1 */
#define H_OFF    83886080ull      /* 16384 x 4096 bf16 = 128 MB */
#define PT_OFF   218103808ull     /* pair_token [16384] int */
#define PG_OFF   218169344ull     /* pair_gate  [16384] float */
#define TI_OFF   218234880ull     /* topk_idx [8192][2] int; reused as ppos after scatter */
#define TG_OFF   218300416ull     /* topk_gate [8192][2] float */
#define ST_OFF   218365952ull     /* counts[8], cursor[8], offs[8], psum[8] */
#define YW_OFF   218370048ull     /* per-pair gemm2 output f32 [16384][1024] = 64 MB (optional) */
#define YW_SZ    67108864ull

typedef __attribute__((address_space(3))) void lds_void;
typedef __attribute__((address_space(1))) const void gbl_void;

__device__ __forceinline__ void gload_lds16(const void* g, void* l) {
  __builtin_amdgcn_global_load_lds((gbl_void*)g, (lds_void*)l, 16, 0, 0);
}

__device__ __forceinline__ u16 f2bf(float f) {
  union { float f; unsigned u; } a; a.f = f;
  unsigned u = a.u;
  return (u16)((u + 0x7FFFu + ((u >> 16) & 1u)) >> 16);  // RNE
}

__global__ __launch_bounds__(256) void cast_f32_bf16(const float* __restrict__ src,
                                                     u16* __restrict__ dst, int n4) {
  int i = blockIdx.x * 256 + threadIdx.x;
  if (i >= n4) return;
  float4 v = ((const float4*)src)[i];
  ushort4 o;
  o.x = f2bf(v.x); o.y = f2bf(v.y); o.z = f2bf(v.z); o.w = f2bf(v.w);
  ((ushort4*)dst)[i] = o;
}

__global__ __launch_bounds__(256) void router_kernel(
    const float* __restrict__ x, const float* __restrict__ rw,
    const float* __restrict__ rb,
    int* __restrict__ tidx, float* __restrict__ tgate,
    int* __restrict__ counts, float* __restrict__ psum)
{
  __shared__ float srw[NE * DM];
  __shared__ float s_psum[NE];
  __shared__ int s_cnt[NE];

  for (int i = threadIdx.x; i < NE * DM; i += 256) srw[i] = rw[i];
  if (threadIdx.x < NE) { s_psum[threadIdx.x] = 0.f; s_cnt[threadIdx.x] = 0; }
  __syncthreads();

  const int wave = threadIdx.x >> 6;
  const int lane = threadIdx.x & 63;
  const int t = blockIdx.x * 4 + wave;

  float xv[16];
#pragma unroll
  for (int i = 0; i < 16; i++) xv[i] = x[(size_t)t * DM + i * 64 + lane];

  float logits[8];
#pragma unroll
  for (int e = 0; e < 8; e++) {
    float p = 0.f;
#pragma unroll
    for (int i = 0; i < 16; i++) p += xv[i] * srw[e * DM + i * 64 + lane];
#pragma unroll
    for (int o = 32; o > 0; o >>= 1) p += __shfl_xor(p, o, 64);
    logits[e] = p;
  }

  if (lane == 0) {
    float pe[8];
    float mx = -1e30f;
    for (int e = 0; e < 8; e++) { logits[e] += rb[e]; mx = fmaxf(mx, logits[e]); }
    float s = 0.f;
    for (int e = 0; e < 8; e++) { pe[e] = expf(logits[e] - mx); s += pe[e]; }
    float inv = 1.f / s;
    for (int e = 0; e < 8; e++) { pe[e] *= inv; atomicAdd(&s_psum[e], pe[e]); }
    int i0 = 0;
    for (int e = 1; e < 8; e++) if (pe[e] > pe[i0]) i0 = e;        // ties -> lowest idx
    int i1 = (i0 == 0) ? 1 : 0;
    for (int e = 0; e < 8; e++) if (e != i0 && pe[e] > pe[i1]) i1 = e;
    float g = pe[i0] + pe[i1];
    tidx[t * 2] = i0; tidx[t * 2 + 1] = i1;
    tgate[t * 2] = pe[i0] / g; tgate[t * 2 + 1] = pe[i1] / g;
    atomicAdd(&s_cnt[i0], 1); atomicAdd(&s_cnt[i1], 1);
  }
  __syncthreads();
  if (threadIdx.x < NE) {
    atomicAdd(&counts[threadIdx.x], s_cnt[threadIdx.x]);
    atomicAdd(&psum[threadIdx.x], s_psum[threadIdx.x]);
  }
}

__global__ void offsets_kernel(const int* __restrict__ counts, int* __restrict__ offs) {
  if (threadIdx.x == 0) {
    int a = 0;
    for (int e = 0; e < NE; e++) { offs[e] = a; a += counts[e]; }
  }
}

// ppos may alias tidx (read-then-overwrite per thread) -> no __restrict__ on those.
__global__ __launch_bounds__(256) void scatter_kernel(
    const int* tidx, const float* __restrict__ tgate,
    const int* __restrict__ offs, int* __restrict__ cursor,
    int* __restrict__ ptok, float* __restrict__ pgate, int* ppos)
{
  int t = blockIdx.x * 256 + threadIdx.x;
  int e0 = tidx[t * 2], e1 = tidx[t * 2 + 1];
  float g0 = tgate[t * 2], g1 = tgate[t * 2 + 1];
  int p0 = offs[e0] + atomicAdd(&cursor[e0], 1);
  int p1 = offs[e1] + atomicAdd(&cursor[e1], 1);
  ptok[p0] = t; pgate[p0] = g0;
  ptok[p1] = t; pgate[p1] = g1;
  ppos[t * 2] = p0; ppos[t * 2 + 1] = p1;
}

// ---------------------------------------------------------------------------
// 256x256 tile, BK=64, 8 waves (2M x 4N), 8-phase pipelined K-loop.
// LDS: 2 buffers x (A 256x64 + B 256x64) bf16 = 128 KiB.
// Half-tile = 128 rows x 64 k = 16 KiB = 512 thr x 16B x 2 loads.
// Swizzle: 16B chunk c of row r stored at chunk-pos c ^ (r&7); gload_lds dst
// is lane-linear so the SOURCE chunk is permuted per lane. Fragment ds_reads
// then alias 2 lanes / 16B slot (2-way = free).
// vmcnt discipline: phases 4/8 wait vmcnt(4) = "all but newest 2 half-tile
// stages complete" (robust even if compiler issues extra vmem earlier, since
// waiting only forces OLDER ops complete). Tail iteration drains to 0.
// Compiler fences around each raw s_barrier pin C++ LDS ops to their phase.
// ---------------------------------------------------------------------------

#define FENCE asm volatile("" ::: "memory")
#define BAR  do { FENCE; __builtin_amdgcn_s_barrier(); FENCE; } while (0)
#define VMW4 asm volatile("s_waitcnt vmcnt(4)" ::: "memory")
#define VMW0 asm volatile("s_waitcnt vmcnt(0)" ::: "memory")

#define G256_DECLS                                                             \
  __shared__ __align__(16) u16 sm[65536]; /* 128 KiB */                        \
  const int tid = threadIdx.x;                                                 \
  const int lane = tid & 63;                                                   \
  const int wave = tid >> 6;                                                   \
  const int wm = wave & 1, wn = wave >> 1;                                     \
  const int q = lane >> 4, ml = lane & 15;                                     \
  const int swz0 = (q ^ (ml & 7)) * 8;        /* kk=0 chunk (u16 units) */     \
  const int swz1 = ((4 + q) ^ (ml & 7)) * 8;  /* kk=1 chunk */                 \
  const int baseA = wm * 8192 + ml * 64;                                       \
  const int baseB = 16384 + (wn >> 1) * 8192 + (wn & 1) * 4096 + ml * 64;      \
  const int cs = ((tid & 7) ^ ((tid >> 3) & 7)) * 8; /* staging src chunk */   \
  const int srow = tid >> 3; /* 0..63, staged rows srow and srow+64 */         \
  f32x4 acc[8][4];                                                             \
  { const f32x4 z_ = {0.f, 0.f, 0.f, 0.f};                                     \
    _Pragma("unroll") for (int i_ = 0; i_ < 8; i_++)                           \
      _Pragma("unroll") for (int j_ = 0; j_ < 4; j_++) acc[i_][j_] = z_; }     \
  bf16x8 areg[4][2], breg[4][2];

#define STAGE_A(buf, half, k0)                                                 \
  { u16* d_ = sm + (buf) * 32768 + (half) * 8192 + tid * 8;                    \
    gload_lds16(aP[half][0] + (k0), d_);                                       \
    gload_lds16(aP[half][1] + (k0), d_ + 4096); }

#define STAGE_B(buf, half, k0, KD)                                             \
  { u16* d_ = sm + (buf) * 32768 + 16384 + (half) * 8192 + tid * 8;            \
    gload_lds16(bB + (size_t)((half) * 128) * (KD) + (k0), d_);                \
    gload_lds16(bB + (size_t)((half) * 128 + 64) * (KD) + (k0), d_ + 4096); }

#define READ_A(buf, mh)                                                        \
  _Pragma("unroll") for (int m_ = 0; m_ < 4; m_++) {                           \
    areg[m_][0] = *(const bf16x8*)&sm[(buf) * 32768 + baseA +                  \
                                      ((mh) * 4 + m_) * 1024 + swz0];          \
    areg[m_][1] = *(const bf16x8*)&sm[(buf) * 32768 + baseA +                  \
                                      ((mh) * 4 + m_) * 1024 + swz1];          \
  }

#define READ_B(buf, nh)                                                        \
  _Pragma("unroll") for (int n_ = 0; n_ < 2; n_++) {                           \
    breg[(nh) * 2 + n_][0] = *(const bf16x8*)&sm[(buf) * 32768 + baseB +       \
                                      ((nh) * 2 + n_) * 1024 + swz0];          \
    breg[(nh) * 2 + n_][1] = *(const bf16x8*)&sm[(buf) * 32768 + baseB +       \
                                      ((nh) * 2 + n_) * 1024 + swz1];          \
  }

#define MFMA_Q(mh, nh)                                                         \
  __builtin_amdgcn_s_setprio(1);                                               \
  _Pragma("unroll") for (int m_ = 0; m_ < 4; m_++)                             \
    _Pragma("unroll") for (int n_ = 0; n_ < 2; n_++) {                         \
      acc[(mh)*4+m_][(nh)*2+n_] = __builtin_amdgcn_mfma_f32_16x16x32_bf16(     \
          areg[m_][0], breg[(nh)*2+n_][0], acc[(mh)*4+m_][(nh)*2+n_], 0,0,0);  \
      acc[(mh)*4+m_][(nh)*2+n_] = __builtin_amdgcn_mfma_f32_16x16x32_bf16(     \
          areg[m_][1], breg[(nh)*2+n_][1], acc[(mh)*4+m_][(nh)*2+n_], 0,0,0);  \
    }                                                                          \
  __builtin_amdgcn_s_setprio(0);

// One iteration = 2 K-tiles (buf0 in ph1-4, buf1 in ph5-8).
// Stage plan (iter i, t=2i): ph1 A1(t+1)->b1, ph2 B1(t+1)->b1, ph3 B0(t+2)->b0,
// ph4 A0(t+2)->b0, ph5 A1(t+2)->b0, ph6 B1(t+2)->b0, ph7 B0(t+3)->b1,
// ph8 A0(t+3)->b1.  Each slot is staged only after the barrier following its
// last ds_read; vmcnt(4) at ph4/ph8 completes exactly the tile first read at
// the next half-iteration while keeping the newest 4 loads in flight.
#define G256_ITER(KD, k1, k2, k3, ST)                                          \
  READ_A(0, 0) READ_B(0, 0)                                                    \
  STAGE_A(1, 1, (k1))                                                          \
  BAR; MFMA_Q(0, 0) BAR;                                                       \
  READ_B(0, 1)                                                                 \
  STAGE_B(1, 1, (k1), KD)                                                      \
  BAR; MFMA_Q(0, 1) BAR;                                                       \
  READ_A(0, 1)                                                                 \
  if (ST) STAGE_B(0, 0, (k2), KD)                                              \
  BAR; MFMA_Q(1, 1) BAR;                                                       \
  if (ST) STAGE_A(0, 0, (k2))                                                  \
  BAR; MFMA_Q(1, 0)                                                            \
  if (ST) { VMW4; } else { VMW0; }                                             \
  BAR;                                                                         \
  READ_A(1, 0) READ_B(1, 0)                                                    \
  if (ST) STAGE_A(0, 1, (k2))                                                  \
  BAR; MFMA_Q(0, 0) BAR;                                                       \
  READ_B(1, 1)                                                                 \
  if (ST) STAGE_B(0, 1, (k2), KD)                                              \
  BAR; MFMA_Q(0, 1) BAR;                                                       \
  READ_A(1, 1)                                                                 \
  if (ST) STAGE_B(1, 0, (k3), KD)                                              \
  BAR; MFMA_Q(1, 1) BAR;                                                       \
  if (ST) STAGE_A(1, 0, (k3))                                                  \
  BAR; MFMA_Q(1, 0)                                                            \
  if (ST) { VMW4; }                                                            \
  BAR;

#define G256_KLOOP(KD)                                                         \
  STAGE_B(0, 0, 0, KD) STAGE_A(0, 0, 0)                                        \
  STAGE_A(0, 1, 0) STAGE_B(0, 1, 0, KD)                                        \
  STAGE_B(1, 0, 64, KD) STAGE_A(1, 0, 64)                                      \
  VMW4; BAR;                                                                   \
  for (int it_ = 0; it_ < (KD) / 128 - 1; ++it_) {                             \
    const int kb_ = it_ * 128;                                                 \
    G256_ITER(KD, kb_ + 64, kb_ + 128, kb_ + 192, 1)                           \
  }                                                                            \
  G256_ITER(KD, (KD) - 64, 0, 0, 0)

// GEMM1: h[p, j] = relu( sum_k xb[tok(p), k] * w1b[e, j, k] + b1[e, j] )
__global__ __launch_bounds__(512, 2) void gemm1_kernel(
    const u16* __restrict__ xb, const u16* __restrict__ w1b,
    const float* __restrict__ b1, const int* __restrict__ ptok,
    const int* __restrict__ offs, const int* __restrict__ counts,
    u16* __restrict__ h)
{
  const int e = blockIdx.z;
  const int cnt = counts[e];
  const int row0 = blockIdx.y * 256;
  if (row0 >= cnt) return;
  const int off = offs[e];
  const int col0 = blockIdx.x * 256;

  G256_DECLS

  const u16* aP[2][2];
#pragma unroll
  for (int a_ = 0; a_ < 2; a_++)
#pragma unroll
    for (int j_ = 0; j_ < 2; j_++) {
      int p = row0 + a_ * 128 + srow + j_ * 64;
      int tk = ptok[off + (p < cnt ? p : 0)];
      aP[a_][j_] = xb + (size_t)tk * DM + cs;
    }
  const u16* bB = w1b + ((size_t)e * DH + col0 + srow) * DM + cs;

  G256_KLOOP(DM)

#pragma unroll
  for (int M = 0; M < 8; M++) {
#pragma unroll
    for (int r_ = 0; r_ < 4; r_++) {
      int prow = row0 + wm * 128 + M * 16 + q * 4 + r_;
      if (prow < cnt) {
#pragma unroll
        for (int N = 0; N < 4; N++) {
          int gcol = col0 + wn * 64 + N * 16 + ml;
          float v = acc[M][N][r_] + b1[e * DH + gcol];
          h[(size_t)(off + prow) * DH + gcol] = f2bf(fmaxf(v, 0.f));
        }
      }
    }
  }
}

// GEMM2: y[p, j] = gate(p) * ( sum_k h[p, k] * w2b[e, j, k] + b2[e, j] )
// use_yw: store per-pair rows into yw (combined later); else atomicAdd into out.
__global__ __launch_bounds__(512, 2) void gemm2_kernel(
    const u16* __restrict__ h, const u16* __restrict__ w2b,
    const float* __restrict__ b2, const int* __restrict__ ptok,
    const float* __restrict__ pgate,
    const int* __restrict__ offs, const int* __restrict__ counts,
    float* __restrict__ yw, float* __restrict__ out, int use_yw)
{
  const int e = blockIdx.z;
  const int cnt = counts[e];
  const int row0 = blockIdx.y * 256;
  if (row0 >= cnt) return;
  const int off = offs[e];
  const int col0 = blockIdx.x * 256;

  G256_DECLS

  const u16* aP[2][2];
#pragma unroll
  for (int a_ = 0; a_ < 2; a_++)
#pragma unroll
    for (int j_ = 0; j_ < 2; j_++) {
      int p = row0 + a_ * 128 + srow + j_ * 64;
      aP[a_][j_] = h + (size_t)(off + (p < cnt ? p : 0)) * DH + cs;
    }
  const u16* bB = w2b + ((size_t)e * DO + col0 + srow) * DH + cs;

  G256_KLOOP(DH)

#pragma unroll
  for (int M = 0; M < 8; M++) {
#pragma unroll
    for (int r_ = 0; r_ < 4; r_++) {
      int prow = row0 + wm * 128 + M * 16 + q * 4 + r_;
      if (prow < cnt) {
        int pr = off + prow;
        float g = pgate[pr];
        if (use_yw) {
#pragma unroll
          for (int N = 0; N < 4; N++) {
            int gcol = col0 + wn * 64 + N * 16 + ml;
            yw[(size_t)pr * DO + gcol] = g * (acc[M][N][r_] + b2[e * DO + gcol]);
          }
        } else {
          int t = ptok[pr];
#pragma unroll
          for (int N = 0; N < 4; N++) {
            int gcol = col0 + wn * 64 + N * 16 + ml;
            atomicAdd(&out[(size_t)t * DO + gcol], g * (acc[M][N][r_] + b2[e * DO + gcol]));
          }
        }
      }
    }
  }
}

// out[t, :] = yw[p0, :] + yw[p1, :]   (gates already applied in gemm2)
__global__ __launch_bounds__(256) void combine_kernel(
    const float* __restrict__ yw, const int* __restrict__ ppos,
    float* __restrict__ out)
{
  int t = blockIdx.x;
  int j = threadIdx.x;  // 256 threads x float4 = 1024 cols
  int p0 = ppos[t * 2], p1 = ppos[t * 2 + 1];
  float4 a = ((const float4*)(yw + (size_t)p0 * DO))[j];
  float4 b = ((const float4*)(yw + (size_t)p1 * DO))[j];
  float4 o;
  o.x = a.x + b.x; o.y = a.y + b.y; o.z = a.z + b.z; o.w = a.w + b.w;
  ((float4*)(out + (size_t)t * DO))[j] = o;
}

__global__ void loss_kernel(const int* __restrict__ counts, const float* __restrict__ psum,
                            float* __restrict__ out, size_t idx, int T) {
  if (threadIdx.x == 0 && blockIdx.x == 0) {
    float s = 0.f;
    for (int e = 0; e < NE; e++)
      s += ((float)counts[e] / (float)(T * 2)) * (psum[e] / (float)T);
    out[idx] = 0.01f * 8.0f * s;
  }
}

extern "C" void kernel_launch(void* const* d_in, const int* in_sizes, int n_in,
                              void* d_out, int out_size, void* d_ws, size_t ws_size,
                              hipStream_t stream) {
  const float* x  = (const float*)d_in[0];
  const float* rw = (const float*)d_in[1];
  const float* rb = (const float*)d_in[2];
  const float* w1 = (const float*)d_in[3];
  const float* b1 = (const float*)d_in[4];
  const float* w2 = (const float*)d_in[5];
  const float* b2 = (const float*)d_in[6];
  float* out = (float*)d_out;
  char* ws = (char*)d_ws;

  u16* xb    = (u16*)(ws + XB_OFF);
  u16* w1b   = (u16*)(ws + W1B_OFF);
  u16* w2b   = (u16*)(ws + W2B_OFF);
  u16* h     = (u16*)(ws + H_OFF);
  int* ptok  = (int*)(ws + PT_OFF);
  float* pgate = (float*)(ws + PG_OFF);
  int* tidx  = (int*)(ws + TI_OFF);
  float* tgate = (float*)(ws + TG_OFF);
  int* counts = (int*)(ws + ST_OFF);
  int* cursor = (int*)(ws + ST_OFF + 32);
  int* offs   = (int*)(ws + ST_OFF + 64);
  float* psum = (float*)(ws + ST_OFF + 96);
  int* ppos   = tidx;  // tidx is dead after scatter; reuse as pair-position map
  float* yw   = (float*)(ws + YW_OFF);

  const bool use_yw = ws_size >= YW_OFF + YW_SZ;

  if (!use_yw)
    hipMemsetAsync(d_out, 0, (size_t)out_size * sizeof(float), stream);
  hipMemsetAsync(ws + ST_OFF, 0, 256, stream);

  cast_f32_bf16<<<(T_TOKENS * DM / 4 + 255) / 256, 256, 0, stream>>>(x, xb, T_TOKENS * DM / 4);
  cast_f32_bf16<<<(NE * DH * DM / 4 + 255) / 256, 256, 0, stream>>>(w1, w1b, NE * DH * DM / 4);

  router_kernel<<<T_TOKENS / 4, 256, 0, stream>>>(x, rw, rb, tidx, tgate, counts, psum);
  offsets_kernel<<<1, 64, 0, stream>>>(counts, offs);
  scatter_kernel<<<T_TOKENS / 256, 256, 0, stream>>>(tidx, tgate, offs, cursor, ptok, pgate, ppos);

  gemm1_kernel<<<dim3(DH / 256, 32, NE), 512, 0, stream>>>(xb, w1b, b1, ptok, offs, counts, h);

  cast_f32_bf16<<<(NE * DO * DH / 4 + 255) / 256, 256, 0, stream>>>(w2, w2b, NE * DO * DH / 4);

  gemm2_kernel<<<dim3(DO / 256, 32, NE), 512, 0, stream>>>(
      h, w2b, b2, ptok, pgate, offs, counts, yw, out, use_yw ? 1 : 0);

  if (use_yw)
    combine_kernel<<<T_TOKENS, 256, 0, stream>>>(yw, ppos, out);

  loss_kernel<<<1, 1, 0, stream>>>(counts, psum, out, (size_t)out_size - 1, T_TOKENS);
}